// Round 8
// baseline (299.564 us; speedup 1.0000x reference)
//
#include <hip/hip_runtime.h>
#include <hip/hip_bf16.h>
#include <cstddef>
#include <cstdint>

#define BS   16
#define SLEN 512
#define DM   512
#define NH   8
#define DK   64
#define DC   21

typedef __attribute__((ext_vector_type(8))) short short8;     // 8 bf16 = 4 VGPR
typedef __attribute__((ext_vector_type(4))) float f32x4;
typedef __attribute__((ext_vector_type(8))) _Float16 h16x8;   // 8 fp16 = 4 VGPR
typedef _Float16 h16x4a __attribute__((ext_vector_type(4), may_alias)); // aliasing-safe bias load

__device__ inline unsigned pack_bf16(float a, float b) {
    unsigned ua = __builtin_bit_cast(unsigned, a);
    unsigned ub = __builtin_bit_cast(unsigned, b);
    ua = (ua + 0x7fffu + ((ua >> 16) & 1u)) >> 16;            // RNE
    ub = (ub + 0x7fffu + ((ub >> 16) & 1u)) >> 16;
    return ua | (ub << 16);
}
__device__ inline unsigned cvt2(float a, float b) { return pack_bf16(a, b); }
__device__ inline ushort bf16_1(float a) { return (ushort)(pack_bf16(a, 0.f) & 0xffffu); }
__device__ inline unsigned pk_f16(float a, float b) {
    return __builtin_bit_cast(unsigned, __builtin_amdgcn_cvt_pkrtz(a, b));
}

// fp16 bias chunk for (bh, q16-slice): occupies the SAME 32 KiB as the owning
// wave's fp32 attn write range (rows q16..q16+15). Segmented layout:
//   bias entry (ql, k) -> fp16 elem  1024*ql + 64*(k>>5) + (k&31)
// i.e. block c2=k>>5 lives in the first 64 bytes of the 128-byte span that
// iteration c2's fp32 stores (cols [32c2,32c2+32)) cover. Descending-c2 pass 2
// therefore clobbers only segments whose reads are already done; within an
// iteration, reads (may_alias) precede stores in program order.
__device__ __host__ inline size_t bias_chunk_base(int bh, int q16) {
    return 2 * (((size_t)bh * SLEN + (size_t)q16) * SLEN);
}

// ---------------------------------------------------------------------------
// bf16 MFMA GEMM. MODE 1: fp32 X -> bf16 per-head [bh][s][64].
// MODE 2: fp32 X -> fp16 transposed [bh][64][s] (V). MODE 3: bf16 X -> fp32.
// ---------------------------------------------------------------------------
template<int MODE>
__global__ __launch_bounds__(256) void gemm_bf16(
    const void* __restrict__ Xv, const float* __restrict__ W,
    const float* __restrict__ bias, void* __restrict__ outv)
{
    __shared__ alignas(16) ushort Atile[64 * 64];
    __shared__ alignas(16) ushort Btile[128 * 64];

    const float*  Xf = (const float*)Xv;
    const ushort* Xb = (const ushort*)Xv;

    const int tid = threadIdx.x;
    const int wave = tid >> 6, lane = tid & 63;
    const int lq = lane & 15, lg = lane >> 4;
    const int wr = wave >> 1, wc = wave & 1;
    const int m0 = blockIdx.x * 64;
    const int n0 = blockIdx.y * 128;

    f32x4 acc[2][4];
#pragma unroll
    for (int i = 0; i < 2; ++i)
#pragma unroll
        for (int j = 0; j < 4; ++j) acc[i][j] = (f32x4){0.f, 0.f, 0.f, 0.f};

    float4 pa[2][2], pb[4][2];
    uint4  qa[2];

#define LOAD_A(K0)                                                              \
    if (MODE == 3) {                                                            \
        _Pragma("unroll")                                                       \
        for (int i = 0; i < 2; ++i) {                                           \
            const int P = tid + 256 * i;                                        \
            const int row = P >> 3, sl = P & 7;                                 \
            qa[i] = *(const uint4*)&Xb[(size_t)(m0 + row) * 512 + (K0) + sl * 8]; \
        }                                                                       \
    } else {                                                                    \
        _Pragma("unroll")                                                       \
        for (int i = 0; i < 2; ++i) {                                           \
            const int P = tid + 256 * i;                                        \
            const int row = P >> 3, cp = P & 7;                                 \
            const float4* s = (const float4*)&Xf[(size_t)(m0 + row) * 512 + (K0) + cp * 8]; \
            pa[i][0] = s[0]; pa[i][1] = s[1];                                   \
        }                                                                       \
    }
#define LOAD_B(K0)                                                              \
    _Pragma("unroll")                                                           \
    for (int i = 0; i < 4; ++i) {                                               \
        const int P = tid + 256 * i;                                            \
        const int row = P >> 3, cp = P & 7;                                     \
        const float4* s = (const float4*)&W[(size_t)(n0 + row) * 512 + (K0) + cp * 8]; \
        pb[i][0] = s[0]; pb[i][1] = s[1];                                       \
    }

    LOAD_A(0)
    LOAD_B(0)

    for (int it = 0; it < 8; ++it) {
        __syncthreads();
        if (MODE == 3) {
#pragma unroll
            for (int i = 0; i < 2; ++i) {
                const int P = tid + 256 * i;
                const int row = P >> 3, sl = P & 7;
                *(uint4*)((char*)Atile + row * 128 + 16 * (sl ^ (row & 7))) = qa[i];
            }
        } else {
#pragma unroll
            for (int i = 0; i < 2; ++i) {
                const int P = tid + 256 * i;
                const int row = P >> 3, cp = P & 7;
                uint4 w;
                w.x = cvt2(pa[i][0].x, pa[i][0].y);
                w.y = cvt2(pa[i][0].z, pa[i][0].w);
                w.z = cvt2(pa[i][1].x, pa[i][1].y);
                w.w = cvt2(pa[i][1].z, pa[i][1].w);
                *(uint4*)((char*)Atile + row * 128 + 16 * (cp ^ (row & 7))) = w;
            }
        }
#pragma unroll
        for (int i = 0; i < 4; ++i) {
            const int P = tid + 256 * i;
            const int row = P >> 3, cp = P & 7;
            uint4 w;
            w.x = cvt2(pb[i][0].x, pb[i][0].y);
            w.y = cvt2(pb[i][0].z, pb[i][0].w);
            w.z = cvt2(pb[i][1].x, pb[i][1].y);
            w.w = cvt2(pb[i][1].z, pb[i][1].w);
            *(uint4*)((char*)Btile + row * 128 + 16 * (cp ^ (row & 7))) = w;
        }
        __syncthreads();

        if (it < 7) {
            const int kn = (it + 1) * 64;
            LOAD_A(kn)
            LOAD_B(kn)
        }

        short8 af[2][2], bfr[4][2];
#pragma unroll
        for (int mi = 0; mi < 2; ++mi)
#pragma unroll
            for (int kh = 0; kh < 2; ++kh) {
                const int row = wr * 32 + mi * 16 + lq;
                af[mi][kh] = *(const short8*)((const char*)Atile + row * 128 +
                                              16 * ((kh * 4 + lg) ^ (row & 7)));
            }
#pragma unroll
        for (int ni = 0; ni < 4; ++ni)
#pragma unroll
            for (int kh = 0; kh < 2; ++kh) {
                const int row = wc * 64 + ni * 16 + lq;
                bfr[ni][kh] = *(const short8*)((const char*)Btile + row * 128 +
                                               16 * ((kh * 4 + lg) ^ (row & 7)));
            }
        __builtin_amdgcn_s_setprio(1);
#pragma unroll
        for (int kh = 0; kh < 2; ++kh)
#pragma unroll
            for (int mi = 0; mi < 2; ++mi)
#pragma unroll
                for (int ni = 0; ni < 4; ++ni)
                    acc[mi][ni] = __builtin_amdgcn_mfma_f32_16x16x32_bf16(
                        af[mi][kh], bfr[ni][kh], acc[mi][ni], 0, 0, 0);
        __builtin_amdgcn_s_setprio(0);
    }
#undef LOAD_A
#undef LOAD_B

    if (MODE == 3) {
        float* out = (float*)outv;
#pragma unroll
        for (int mi = 0; mi < 2; ++mi) {
            const int mb = m0 + wr * 32 + mi * 16 + lg * 4;
#pragma unroll
            for (int ni = 0; ni < 4; ++ni) {
                const int n = n0 + wc * 64 + ni * 16 + lq;
                const float bb = bias[n];
#pragma unroll
                for (int r = 0; r < 4; ++r)
                    out[(size_t)(mb + r) * 512 + n] = acc[mi][ni][r] + bb;
            }
        }
    } else if (MODE == 1) {
        ushort* out = (ushort*)outv;
#pragma unroll
        for (int mi = 0; mi < 2; ++mi) {
            const int mb = m0 + wr * 32 + mi * 16 + lg * 4;
#pragma unroll
            for (int ni = 0; ni < 4; ++ni) {
                const int n = n0 + wc * 64 + ni * 16 + lq;
                const int h = n >> 6, d = n & 63;
                const float bb = bias[n];
#pragma unroll
                for (int r = 0; r < 4; ++r) {
                    const int m = mb + r;
                    const int bidx = m >> 9, s = m & 511;
                    out[((size_t)(bidx * NH + h) * SLEN + s) * DK + d] =
                        bf16_1(acc[mi][ni][r] + bb);
                }
            }
        }
    } else {
        // MODE 2: fp16 transposed V [bh][64][s]
        ushort* out = (ushort*)outv;
#pragma unroll
        for (int mi = 0; mi < 2; ++mi) {
            const int mb = m0 + wr * 32 + mi * 16 + lg * 4;
            const int bidx = mb >> 9, s0 = mb & 511;
#pragma unroll
            for (int ni = 0; ni < 4; ++ni) {
                const int n = n0 + wc * 64 + ni * 16 + lq;
                const int h = n >> 6, d = n & 63;
                const float bb = bias[n];
                uint2 pk;
                pk.x = pk_f16(acc[mi][ni][0] + bb, acc[mi][ni][1] + bb);
                pk.y = pk_f16(acc[mi][ni][2] + bb, acc[mi][ni][3] + bb);
                *(uint2*)&out[((size_t)(bidx * NH + h) * DK + d) * SLEN + s0] = pk;
            }
        }
    }
}

// ---------------------------------------------------------------------------
// Bias -> fp16, segmented layout inside the attn region (see bias_chunk_base).
// ---------------------------------------------------------------------------
__global__ __launch_bounds__(512) void bias_kernel(
    const float* __restrict__ dtw, const float* __restrict__ Wd,
    const float* __restrict__ bd, _Float16* __restrict__ bias16)
{
    __shared__ float wdl[NH * DC];
    __shared__ float bdl[NH];
    const int k = threadIdx.x;
    const int q = blockIdx.x;
    const int b = blockIdx.y;
    if (k < NH * DC) wdl[k] = Wd[k];
    if (k < NH) bdl[k] = bd[k];
    __syncthreads();

    float acc[NH];
#pragma unroll
    for (int h = 0; h < NH; ++h) acc[h] = bdl[h];

    const float* p = dtw + ((size_t)b * DC * SLEN + q) * SLEN + k;
#pragma unroll
    for (int c = 0; c < DC; ++c) {
        const float x = p[(size_t)c * SLEN * SLEN];
#pragma unroll
        for (int h = 0; h < NH; ++h) acc[h] += x * wdl[h * DC + c];
    }
    const int q16 = q & ~15, ql = q & 15;
    const size_t seg = 1024 * (size_t)ql + 64 * (size_t)(k >> 5) + (k & 31);
#pragma unroll
    for (int h = 0; h < NH; ++h) {
        const size_t base = bias_chunk_base(b * NH + h, q16);
        bias16[base + seg] = (_Float16)acc[h];
    }
}

// ---------------------------------------------------------------------------
// Two-pass MFMA attention (no sc[32], 8 KB LDS, 3 blocks/CU min).
// Pass 1: QK^T + bias -> sum of exp (no max subtraction; logits bounded ~|s|<3).
// Pass 2 (c2 = 15..0): recompute scores for kt=2c2,2c2+1; write normalized
//   attn fp32 (clobbers ONLY bias segment c2); pack unnormalized e -> fp16;
//   bounce via 1KB/wave double-buffered LDS; PV via f16 MFMA.
// ---------------------------------------------------------------------------
__global__ __launch_bounds__(256, 3) void attn_mfma(
    const ushort* __restrict__ qb, const ushort* __restrict__ kb,
    const ushort* __restrict__ vt, float* __restrict__ attn,
    ushort* __restrict__ concat)
{
    __shared__ alignas(16) ushort Pbuf[4][2][16][32];   // 8 KB total

    const int tid = threadIdx.x;
    const int wave = tid >> 6;
    const int lane = tid & 63;
    const int lq = lane & 15;
    const int lg = lane >> 4;

    // XCD swizzle: 8 consecutive dispatches per XCD share one (b,h)
    const unsigned l = blockIdx.x;
    const int g  = (int)((l & 7) + 8 * (l >> 6));
    const int qt = (int)((l >> 3) & 7);
    const int h = g & 7, b = g >> 3;
    const int bh = b * NH + h;
    const int q0 = qt * 64 + wave * 16;

    const ushort* qptr = qb + ((size_t)bh * SLEN + q0) * DK;
    const ushort* kptr = kb + (size_t)bh * SLEN * DK;
    const ushort* vptr = vt + (size_t)bh * DK * SLEN;   // fp16 bits
    float* attn_b = attn + ((size_t)bh * SLEN + q0) * SLEN;
    // segmented bias: this lane's row base (1024 fp16 per row)
    const _Float16* bias_row =
        (const _Float16*)attn + bias_chunk_base(bh, q0) + 1024 * (size_t)lq;

    const short8 qf0 = *(const short8*)&qptr[(size_t)lq * DK + lg * 8];
    const short8 qf1 = *(const short8*)&qptr[(size_t)lq * DK + lg * 8 + 32];

    // ---- pass 1: sum of exp(scores) ----
    float sum = 0.f;
#pragma unroll 8
    for (int kt = 0; kt < 32; ++kt) {
        const short8 a0 = *(const short8*)&kptr[(size_t)(kt * 16 + lq) * DK + lg * 8];
        const short8 a1 = *(const short8*)&kptr[(size_t)(kt * 16 + lq) * DK + lg * 8 + 32];
        f32x4 c = {0.f, 0.f, 0.f, 0.f};
        c = __builtin_amdgcn_mfma_f32_16x16x32_bf16(a0, qf0, c, 0, 0, 0);
        c = __builtin_amdgcn_mfma_f32_16x16x32_bf16(a1, qf1, c, 0, 0, 0);
        const h16x4a b4 = *(const h16x4a*)&bias_row[64 * (kt >> 1) + 16 * (kt & 1) + 4 * lg];
        const float s0 = c[0] * 0.125f + (float)b4[0];
        const float s1 = c[1] * 0.125f + (float)b4[1];
        const float s2 = c[2] * 0.125f + (float)b4[2];
        const float s3 = c[3] * 0.125f + (float)b4[3];
        sum += (__expf(s0) + __expf(s1)) + (__expf(s2) + __expf(s3));
    }
    sum += __shfl_xor(sum, 16);
    sum += __shfl_xor(sum, 32);
    const float inv = 1.0f / sum;

    // ---- pass 2: recompute + attn write + PV ----
    f32x4 oacc[4] = {{0.f,0.f,0.f,0.f},{0.f,0.f,0.f,0.f},{0.f,0.f,0.f,0.f},{0.f,0.f,0.f,0.f}};

#pragma unroll 2
    for (int c2 = 15; c2 >= 0; --c2) {
        f32x4 ev[2];
#pragma unroll
        for (int t = 0; t < 2; ++t) {
            const int kt = 2 * c2 + t;
            const short8 a0 = *(const short8*)&kptr[(size_t)(kt * 16 + lq) * DK + lg * 8];
            const short8 a1 = *(const short8*)&kptr[(size_t)(kt * 16 + lq) * DK + lg * 8 + 32];
            f32x4 c = {0.f, 0.f, 0.f, 0.f};
            c = __builtin_amdgcn_mfma_f32_16x16x32_bf16(a0, qf0, c, 0, 0, 0);
            c = __builtin_amdgcn_mfma_f32_16x16x32_bf16(a1, qf1, c, 0, 0, 0);
            const h16x4a b4 = *(const h16x4a*)&bias_row[64 * c2 + 16 * t + 4 * lg];
            ev[t][0] = __expf(c[0] * 0.125f + (float)b4[0]);
            ev[t][1] = __expf(c[1] * 0.125f + (float)b4[1]);
            ev[t][2] = __expf(c[2] * 0.125f + (float)b4[2]);
            ev[t][3] = __expf(c[3] * 0.125f + (float)b4[3]);
        }
        // stores strictly after this iteration's bias reads; clobber = segment c2 only
#pragma unroll
        for (int t = 0; t < 2; ++t)
            *(f32x4*)&attn_b[(size_t)lq * SLEN + (2 * c2 + t) * 16 + lg * 4] = ev[t] * inv;

        // pack fp16 (unnormalized) -> LDS bounce
        char* pb = (char*)&Pbuf[wave][c2 & 1][0][0];
#pragma unroll
        for (int t = 0; t < 2; ++t) {
            uint2 pk;
            pk.x = pk_f16(ev[t][0], ev[t][1]);
            pk.y = pk_f16(ev[t][2], ev[t][3]);
            const int slot = (t * 2 + (lg >> 1)) ^ (lq & 3);
            *(uint2*)(pb + lq * 64 + slot * 16 + (lg & 1) * 8) = pk;
        }
        asm volatile("s_waitcnt lgkmcnt(0)" ::: "memory");

        const h16x8 pa = *(const h16x8*)(pb + lq * 64 + (lg ^ (lq & 3)) * 16);
        __builtin_amdgcn_s_setprio(1);
#pragma unroll
        for (int dt = 0; dt < 4; ++dt) {
            const h16x8 vb8 = *(const h16x8*)&vptr[(size_t)(dt * 16 + lq) * SLEN + c2 * 32 + lg * 8];
            oacc[dt] = __builtin_amdgcn_mfma_f32_16x16x32_f16(pa, vb8, oacc[dt], 0, 0, 0);
        }
        __builtin_amdgcn_s_setprio(0);
    }

    // concat in bf16 [b][s][h*64+d]
    ushort* cbase = concat + ((size_t)(b * SLEN + q0)) * DM + h * 64;
#pragma unroll
    for (int r = 0; r < 4; ++r) {
        const float iv = __shfl(inv, lg * 4 + r);
#pragma unroll
        for (int dt = 0; dt < 4; ++dt) {
            cbase[(size_t)(lg * 4 + r) * DM + dt * 16 + lq] = bf16_1(oacc[dt][r] * iv);
        }
    }
}

// ---------------------------------------------------------------------------
extern "C" void kernel_launch(void* const* d_in, const int* in_sizes, int n_in,
                              void* d_out, int out_size, void* d_ws, size_t ws_size,
                              hipStream_t stream)
{
    const float* Q   = (const float*)d_in[0];
    const float* K   = (const float*)d_in[1];
    const float* V   = (const float*)d_in[2];
    const float* dtw = (const float*)d_in[4];
    const float* Wq  = (const float*)d_in[5];
    const float* bq  = (const float*)d_in[6];
    const float* Wk  = (const float*)d_in[7];
    const float* bk  = (const float*)d_in[8];
    const float* Wv  = (const float*)d_in[9];
    const float* bv  = (const float*)d_in[10];
    const float* Wd  = (const float*)d_in[11];
    const float* bd  = (const float*)d_in[12];
    const float* Wo  = (const float*)d_in[13];
    const float* bo  = (const float*)d_in[14];

    float* out  = (float*)d_out;                       // [16,512,512] fp32
    float* attn = out + (size_t)BS * SLEN * DM;        // [16,8,512,512] fp32
    _Float16* bias16 = (_Float16*)attn;                // fp16 bias chunks inside attn region

    const size_t PHS = (size_t)BS * NH * SLEN * DK;    // 4,194,304 elements
    ushort* qb = (ushort*)d_ws;
    ushort* kb = qb + PHS;
    ushort* vt = kb + PHS;                             // fp16 V
    ushort* cb = vt + PHS;                             // concat bf16 [16,512,512]

    const dim3 gemm_grid(128, 4);

    gemm_bf16<1><<<gemm_grid, 256, 0, stream>>>(Q, Wq, bq, qb);
    gemm_bf16<1><<<gemm_grid, 256, 0, stream>>>(K, Wk, bk, kb);
    gemm_bf16<2><<<gemm_grid, 256, 0, stream>>>(V, Wv, bv, vt);

    bias_kernel<<<dim3(SLEN, BS), 512, 0, stream>>>(dtw, Wd, bd, bias16);

    attn_mfma<<<dim3(1024), 256, 0, stream>>>(qb, kb, vt, attn, cb);

    gemm_bf16<3><<<gemm_grid, 256, 0, stream>>>(cb, Wo, bo, out);
}